// Round 1
// baseline (5622.268 us; speedup 1.0000x reference)
//
#include <hip/hip_runtime.h>
#include <hip/hip_bf16.h>
#include <math.h>

// Qwen2 decoder layer, MI355X baseline (fp32 everywhere, correctness-first).
// B=2 S=2048 D=1024 H=16 HKV=4 HD=64 FF=4096 WINDOW=1024
#define BB 2
#define SS 2048
#define DD 1024
#define HH 16
#define HKVN 4
#define HDIM 64
#define FFD 4096
#define WND 1024
#define EPSF 1e-6f

// ---------------- RMSNorm: one block per row ----------------
__global__ __launch_bounds__(256) void rmsnorm_kernel(
    const float* __restrict__ x, const float* __restrict__ w,
    float* __restrict__ out, int d) {
  int row = blockIdx.x;
  const float* xr = x + (size_t)row * d;
  float ss = 0.f;
  for (int i = threadIdx.x; i < d; i += blockDim.x) {
    float v = xr[i];
    ss += v * v;
  }
  __shared__ float red[8];
  for (int o = 32; o > 0; o >>= 1) ss += __shfl_down(ss, o, 64);
  int wid = threadIdx.x >> 6, lane = threadIdx.x & 63;
  if (lane == 0) red[wid] = ss;
  __syncthreads();
  if (threadIdx.x == 0) {
    float t = 0.f;
    int nw = blockDim.x >> 6;
    for (int i = 0; i < nw; i++) t += red[i];
    red[0] = rsqrtf(t / (float)d + EPSF);
  }
  __syncthreads();
  float rs = red[0];
  float* orow = out + (size_t)row * d;
  for (int i = threadIdx.x; i < d; i += blockDim.x) {
    orow[i] = xr[i] * rs * w[i];
  }
}

// ---------------- Generic tiled GEMM: C = A@W (+bias) (+resid) ----------------
// A: MxK row-major, W: KxN row-major. BM=BN=64, BK=16, 256 thr, 4x4 per thread.
__global__ __launch_bounds__(256) void gemm64(
    const float* __restrict__ A, const float* __restrict__ W,
    const float* __restrict__ bias, const float* __restrict__ resid,
    float* __restrict__ C, int M, int N, int K) {
  __shared__ float As[16][65];
  __shared__ float Bs[16][65];
  int tid = threadIdx.x;
  int tx = tid & 15, ty = tid >> 4;
  int row0 = blockIdx.y * 64, col0 = blockIdx.x * 64;
  int la_r = tid >> 2, la_k = (tid & 3) << 2;
  int lb_k = tid >> 4, lb_c = (tid & 15) << 2;
  float acc[4][4] = {};
  const float* Aptr = A + (size_t)(row0 + la_r) * K + la_k;
  const float* Wptr = W + (size_t)lb_k * N + col0 + lb_c;
  for (int k0 = 0; k0 < K; k0 += 16) {
    float4 av = *(const float4*)(Aptr);
    float4 bv = *(const float4*)(Wptr);
    Aptr += 16;
    Wptr += (size_t)16 * N;
    As[la_k + 0][la_r] = av.x;
    As[la_k + 1][la_r] = av.y;
    As[la_k + 2][la_r] = av.z;
    As[la_k + 3][la_r] = av.w;
    Bs[lb_k][lb_c + 0] = bv.x;
    Bs[lb_k][lb_c + 1] = bv.y;
    Bs[lb_k][lb_c + 2] = bv.z;
    Bs[lb_k][lb_c + 3] = bv.w;
    __syncthreads();
#pragma unroll
    for (int kk = 0; kk < 16; kk++) {
      float a[4], b[4];
#pragma unroll
      for (int i = 0; i < 4; i++) a[i] = As[kk][ty * 4 + i];
#pragma unroll
      for (int j = 0; j < 4; j++) b[j] = Bs[kk][tx * 4 + j];
#pragma unroll
      for (int i = 0; i < 4; i++)
#pragma unroll
        for (int j = 0; j < 4; j++) acc[i][j] = fmaf(a[i], b[j], acc[i][j]);
    }
    __syncthreads();
  }
#pragma unroll
  for (int i = 0; i < 4; i++) {
    int r = row0 + ty * 4 + i;
#pragma unroll
    for (int j = 0; j < 4; j++) {
      int c = col0 + tx * 4 + j;
      float v = acc[i][j];
      if (bias) v += bias[c];
      if (resid) v += resid[(size_t)r * N + c];
      C[(size_t)r * N + c] = v;
    }
  }
}

// ---------------- Dual GEMM + SiLU*up epilogue: ACT = silu(A@Wg) * (A@Wu) ----
__global__ __launch_bounds__(256) void gateup_kernel(
    const float* __restrict__ A, const float* __restrict__ Wg,
    const float* __restrict__ Wu, float* __restrict__ ACT, int M, int N,
    int K) {
  __shared__ float As[16][65];
  __shared__ float Gs[16][65];
  __shared__ float Us[16][65];
  int tid = threadIdx.x;
  int tx = tid & 15, ty = tid >> 4;
  int row0 = blockIdx.y * 64, col0 = blockIdx.x * 64;
  int la_r = tid >> 2, la_k = (tid & 3) << 2;
  int lb_k = tid >> 4, lb_c = (tid & 15) << 2;
  float accg[4][4] = {};
  float accu[4][4] = {};
  const float* Aptr = A + (size_t)(row0 + la_r) * K + la_k;
  const float* Gptr = Wg + (size_t)lb_k * N + col0 + lb_c;
  const float* Uptr = Wu + (size_t)lb_k * N + col0 + lb_c;
  for (int k0 = 0; k0 < K; k0 += 16) {
    float4 av = *(const float4*)(Aptr);
    float4 gv = *(const float4*)(Gptr);
    float4 uv = *(const float4*)(Uptr);
    Aptr += 16;
    Gptr += (size_t)16 * N;
    Uptr += (size_t)16 * N;
    As[la_k + 0][la_r] = av.x;
    As[la_k + 1][la_r] = av.y;
    As[la_k + 2][la_r] = av.z;
    As[la_k + 3][la_r] = av.w;
    Gs[lb_k][lb_c + 0] = gv.x;
    Gs[lb_k][lb_c + 1] = gv.y;
    Gs[lb_k][lb_c + 2] = gv.z;
    Gs[lb_k][lb_c + 3] = gv.w;
    Us[lb_k][lb_c + 0] = uv.x;
    Us[lb_k][lb_c + 1] = uv.y;
    Us[lb_k][lb_c + 2] = uv.z;
    Us[lb_k][lb_c + 3] = uv.w;
    __syncthreads();
#pragma unroll
    for (int kk = 0; kk < 16; kk++) {
      float a[4], g[4], u[4];
#pragma unroll
      for (int i = 0; i < 4; i++) a[i] = As[kk][ty * 4 + i];
#pragma unroll
      for (int j = 0; j < 4; j++) g[j] = Gs[kk][tx * 4 + j];
#pragma unroll
      for (int j = 0; j < 4; j++) u[j] = Us[kk][tx * 4 + j];
#pragma unroll
      for (int i = 0; i < 4; i++) {
#pragma unroll
        for (int j = 0; j < 4; j++) {
          accg[i][j] = fmaf(a[i], g[j], accg[i][j]);
          accu[i][j] = fmaf(a[i], u[j], accu[i][j]);
        }
      }
    }
    __syncthreads();
  }
#pragma unroll
  for (int i = 0; i < 4; i++) {
    int r = row0 + ty * 4 + i;
#pragma unroll
    for (int j = 0; j < 4; j++) {
      int c = col0 + tx * 4 + j;
      float g = accg[i][j];
      float s = g / (1.f + __expf(-g));
      ACT[(size_t)r * N + c] = s * accu[i][j];
    }
  }
}

// ---------------- RoPE (in-place on Q and K) ----------------
// q: [B,S,H,HD], k: [B,S,HKV,HD]; cos/sin: [S,HD] with second half duplicated.
__global__ __launch_bounds__(256) void rope_kernel(
    float* __restrict__ q, float* __restrict__ k,
    const float* __restrict__ cos_t, const float* __restrict__ sin_t) {
  int idx = blockIdx.x * blockDim.x + threadIdx.x;
  int d = idx & 31;
  int rest = idx >> 5;
  int head = rest % (HH + HKVN);
  int bs = rest / (HH + HKVN);
  int s = bs % SS;
  float c = cos_t[s * HDIM + d];
  float sn = sin_t[s * HDIM + d];
  float* ptr;
  if (head < HH)
    ptr = q + ((size_t)bs * HH + head) * HDIM;
  else
    ptr = k + ((size_t)bs * HKVN + (head - HH)) * HDIM;
  float x1 = ptr[d];
  float x2 = ptr[d + 32];
  ptr[d] = x1 * c - x2 * sn;
  ptr[d + 32] = x2 * c + x1 * sn;
}

// ---------------- Attention: one wave per query row, online softmax ----------
// Q,O: [B,S,H,HD]; K,V: [B,S,HKV,HD]. Causal + sliding window WND.
__global__ __launch_bounds__(256) void attn_kernel(
    const float* __restrict__ Q, const float* __restrict__ K,
    const float* __restrict__ V, float* __restrict__ O) {
  int wid = threadIdx.x >> 6;
  int lane = threadIdx.x & 63;
  int gw = blockIdx.x * 4 + wid;  // ((b*H + h)*S + i)
  int i = gw % SS;
  int bh = gw / SS;
  int h = bh % HH;
  int b = bh / HH;
  int hk = h / (HH / HKVN);
  const float scale = 0.125f;  // 1/sqrt(64)
  const float* qp = Q + (((size_t)b * SS + i) * HH + h) * HDIM;
  float qv = qp[lane] * scale;
  int jstart = i - (WND - 1);
  if (jstart < 0) jstart = 0;
  float m = -INFINITY, l = 0.f, acc = 0.f;
  const float* Kb = K + (size_t)b * SS * HKVN * HDIM + hk * HDIM + lane;
  const float* Vb = V + (size_t)b * SS * HKVN * HDIM + hk * HDIM + lane;
  for (int j = jstart; j <= i; j++) {
    float t = qv * Kb[(size_t)j * HKVN * HDIM];
    for (int o = 32; o > 0; o >>= 1) t += __shfl_xor(t, o, 64);
    float mn = fmaxf(m, t);
    float corr = __expf(m - mn);  // first iter: exp(-inf)=0
    float p = __expf(t - mn);
    l = l * corr + p;
    acc = acc * corr + p * Vb[(size_t)j * HKVN * HDIM];
    m = mn;
  }
  O[(((size_t)b * SS + i) * HH + h) * HDIM + lane] = acc / l;
}

extern "C" void kernel_launch(void* const* d_in, const int* in_sizes, int n_in,
                              void* d_out, int out_size, void* d_ws,
                              size_t ws_size, hipStream_t stream) {
  const float* hidden = (const float*)d_in[0];
  const float* cos_t = (const float*)d_in[1];
  const float* sin_t = (const float*)d_in[2];
  const float* wq = (const float*)d_in[3];
  const float* bq = (const float*)d_in[4];
  const float* wk = (const float*)d_in[5];
  const float* bk = (const float*)d_in[6];
  const float* wv = (const float*)d_in[7];
  const float* bv = (const float*)d_in[8];
  const float* wo = (const float*)d_in[9];
  const float* ln1 = (const float*)d_in[10];
  const float* ln2 = (const float*)d_in[11];
  const float* wg = (const float*)d_in[12];
  const float* wu = (const float*)d_in[13];
  const float* wd = (const float*)d_in[14];
  float* out = (float*)d_out;
  float* ws = (float*)d_ws;

  const int M = BB * SS;  // 4096 rows
  // Workspace layout (floats). Total = 4M+4M+1M+1M+4M+16M = 30M floats = 120MB.
  float* A_norm = ws;                              // [M, D]
  float* Qb = A_norm + (size_t)M * DD;             // [B,S,H,HD]
  float* Kb = Qb + (size_t)M * DD;                 // [B,S,HKV,HD]
  float* Vb = Kb + (size_t)M * HKVN * HDIM;        // [B,S,HKV,HD]
  float* CTX = Vb + (size_t)M * HKVN * HDIM;       // [M, D]
  float* ACT = CTX + (size_t)M * DD;               // [M, FF]
  float* HATT = out;  // residual2 lives in d_out (read-before-write in epilogue)

  // 1) RMSNorm 1
  rmsnorm_kernel<<<M, 256, 0, stream>>>(hidden, ln1, A_norm, DD);
  // 2) QKV projections
  gemm64<<<dim3((HH * HDIM) / 64, M / 64), 256, 0, stream>>>(
      A_norm, wq, bq, nullptr, Qb, M, HH * HDIM, DD);
  gemm64<<<dim3((HKVN * HDIM) / 64, M / 64), 256, 0, stream>>>(
      A_norm, wk, bk, nullptr, Kb, M, HKVN * HDIM, DD);
  gemm64<<<dim3((HKVN * HDIM) / 64, M / 64), 256, 0, stream>>>(
      A_norm, wv, bv, nullptr, Vb, M, HKVN * HDIM, DD);
  // 3) RoPE on Q and K (in place)
  rope_kernel<<<(BB * SS * (HH + HKVN) * 32) / 256, 256, 0, stream>>>(
      Qb, Kb, cos_t, sin_t);
  // 4) Attention (GQA, causal, sliding window)
  attn_kernel<<<(BB * HH * SS) / 4, 256, 0, stream>>>(Qb, Kb, Vb, CTX);
  // 5) Output projection + residual -> HATT (= d_out)
  gemm64<<<dim3(DD / 64, M / 64), 256, 0, stream>>>(CTX, wo, nullptr, hidden,
                                                    HATT, M, DD, DD);
  // 6) RMSNorm 2
  rmsnorm_kernel<<<M, 256, 0, stream>>>(HATT, ln2, A_norm, DD);
  // 7) MLP gate/up fused with SiLU*up
  gateup_kernel<<<dim3(FFD / 64, M / 64), 256, 0, stream>>>(A_norm, wg, wu, ACT,
                                                            M, FFD, DD);
  // 8) MLP down + residual2 -> out
  gemm64<<<dim3(DD / 64, M / 64), 256, 0, stream>>>(ACT, wd, nullptr, HATT, out,
                                                    M, DD, FFD);
}

// Round 2
// 4139.008 us; speedup vs baseline: 1.3584x; 1.3584x over previous
//
#include <hip/hip_runtime.h>
#include <hip/hip_bf16.h>
#include <math.h>

// Qwen2 decoder layer, MI355X. Round 1: tiled wave-parallel attention (fp32).
// B=2 S=2048 D=1024 H=16 HKV=4 HD=64 FF=4096 WINDOW=1024
#define BB 2
#define SS 2048
#define DD 1024
#define HH 16
#define HKVN 4
#define HDIM 64
#define FFD 4096
#define WND 1024
#define EPSF 1e-6f

// ---------------- RMSNorm: one block per row ----------------
__global__ __launch_bounds__(256) void rmsnorm_kernel(
    const float* __restrict__ x, const float* __restrict__ w,
    float* __restrict__ out, int d) {
  int row = blockIdx.x;
  const float* xr = x + (size_t)row * d;
  float ss = 0.f;
  for (int i = threadIdx.x; i < d; i += blockDim.x) {
    float v = xr[i];
    ss += v * v;
  }
  __shared__ float red[8];
  for (int o = 32; o > 0; o >>= 1) ss += __shfl_down(ss, o, 64);
  int wid = threadIdx.x >> 6, lane = threadIdx.x & 63;
  if (lane == 0) red[wid] = ss;
  __syncthreads();
  if (threadIdx.x == 0) {
    float t = 0.f;
    int nw = blockDim.x >> 6;
    for (int i = 0; i < nw; i++) t += red[i];
    red[0] = rsqrtf(t / (float)d + EPSF);
  }
  __syncthreads();
  float rs = red[0];
  float* orow = out + (size_t)row * d;
  for (int i = threadIdx.x; i < d; i += blockDim.x) {
    orow[i] = xr[i] * rs * w[i];
  }
}

// ---------------- Generic tiled GEMM: C = A@W (+bias) (+resid) ----------------
__global__ __launch_bounds__(256) void gemm64(
    const float* __restrict__ A, const float* __restrict__ W,
    const float* __restrict__ bias, const float* __restrict__ resid,
    float* __restrict__ C, int M, int N, int K) {
  __shared__ float As[16][65];
  __shared__ float Bs[16][65];
  int tid = threadIdx.x;
  int tx = tid & 15, ty = tid >> 4;
  int row0 = blockIdx.y * 64, col0 = blockIdx.x * 64;
  int la_r = tid >> 2, la_k = (tid & 3) << 2;
  int lb_k = tid >> 4, lb_c = (tid & 15) << 2;
  float acc[4][4] = {};
  const float* Aptr = A + (size_t)(row0 + la_r) * K + la_k;
  const float* Wptr = W + (size_t)lb_k * N + col0 + lb_c;
  for (int k0 = 0; k0 < K; k0 += 16) {
    float4 av = *(const float4*)(Aptr);
    float4 bv = *(const float4*)(Wptr);
    Aptr += 16;
    Wptr += (size_t)16 * N;
    As[la_k + 0][la_r] = av.x;
    As[la_k + 1][la_r] = av.y;
    As[la_k + 2][la_r] = av.z;
    As[la_k + 3][la_r] = av.w;
    Bs[lb_k][lb_c + 0] = bv.x;
    Bs[lb_k][lb_c + 1] = bv.y;
    Bs[lb_k][lb_c + 2] = bv.z;
    Bs[lb_k][lb_c + 3] = bv.w;
    __syncthreads();
#pragma unroll
    for (int kk = 0; kk < 16; kk++) {
      float a[4], b[4];
#pragma unroll
      for (int i = 0; i < 4; i++) a[i] = As[kk][ty * 4 + i];
#pragma unroll
      for (int j = 0; j < 4; j++) b[j] = Bs[kk][tx * 4 + j];
#pragma unroll
      for (int i = 0; i < 4; i++)
#pragma unroll
        for (int j = 0; j < 4; j++) acc[i][j] = fmaf(a[i], b[j], acc[i][j]);
    }
    __syncthreads();
  }
#pragma unroll
  for (int i = 0; i < 4; i++) {
    int r = row0 + ty * 4 + i;
#pragma unroll
    for (int j = 0; j < 4; j++) {
      int c = col0 + tx * 4 + j;
      float v = acc[i][j];
      if (bias) v += bias[c];
      if (resid) v += resid[(size_t)r * N + c];
      C[(size_t)r * N + c] = v;
    }
  }
}

// ---------------- Dual GEMM + SiLU*up epilogue: ACT = silu(A@Wg) * (A@Wu) ----
__global__ __launch_bounds__(256) void gateup_kernel(
    const float* __restrict__ A, const float* __restrict__ Wg,
    const float* __restrict__ Wu, float* __restrict__ ACT, int M, int N,
    int K) {
  __shared__ float As[16][65];
  __shared__ float Gs[16][65];
  __shared__ float Us[16][65];
  int tid = threadIdx.x;
  int tx = tid & 15, ty = tid >> 4;
  int row0 = blockIdx.y * 64, col0 = blockIdx.x * 64;
  int la_r = tid >> 2, la_k = (tid & 3) << 2;
  int lb_k = tid >> 4, lb_c = (tid & 15) << 2;
  float accg[4][4] = {};
  float accu[4][4] = {};
  const float* Aptr = A + (size_t)(row0 + la_r) * K + la_k;
  const float* Gptr = Wg + (size_t)lb_k * N + col0 + lb_c;
  const float* Uptr = Wu + (size_t)lb_k * N + col0 + lb_c;
  for (int k0 = 0; k0 < K; k0 += 16) {
    float4 av = *(const float4*)(Aptr);
    float4 gv = *(const float4*)(Gptr);
    float4 uv = *(const float4*)(Uptr);
    Aptr += 16;
    Gptr += (size_t)16 * N;
    Uptr += (size_t)16 * N;
    As[la_k + 0][la_r] = av.x;
    As[la_k + 1][la_r] = av.y;
    As[la_k + 2][la_r] = av.z;
    As[la_k + 3][la_r] = av.w;
    Gs[lb_k][lb_c + 0] = gv.x;
    Gs[lb_k][lb_c + 1] = gv.y;
    Gs[lb_k][lb_c + 2] = gv.z;
    Gs[lb_k][lb_c + 3] = gv.w;
    Us[lb_k][lb_c + 0] = uv.x;
    Us[lb_k][lb_c + 1] = uv.y;
    Us[lb_k][lb_c + 2] = uv.z;
    Us[lb_k][lb_c + 3] = uv.w;
    __syncthreads();
#pragma unroll
    for (int kk = 0; kk < 16; kk++) {
      float a[4], g[4], u[4];
#pragma unroll
      for (int i = 0; i < 4; i++) a[i] = As[kk][ty * 4 + i];
#pragma unroll
      for (int j = 0; j < 4; j++) g[j] = Gs[kk][tx * 4 + j];
#pragma unroll
      for (int j = 0; j < 4; j++) u[j] = Us[kk][tx * 4 + j];
#pragma unroll
      for (int i = 0; i < 4; i++) {
#pragma unroll
        for (int j = 0; j < 4; j++) {
          accg[i][j] = fmaf(a[i], g[j], accg[i][j]);
          accu[i][j] = fmaf(a[i], u[j], accu[i][j]);
        }
      }
    }
    __syncthreads();
  }
#pragma unroll
  for (int i = 0; i < 4; i++) {
    int r = row0 + ty * 4 + i;
#pragma unroll
    for (int j = 0; j < 4; j++) {
      int c = col0 + tx * 4 + j;
      float g = accg[i][j];
      float s = g / (1.f + __expf(-g));
      ACT[(size_t)r * N + c] = s * accu[i][j];
    }
  }
}

// ---------------- RoPE (in-place on Q and K) ----------------
__global__ __launch_bounds__(256) void rope_kernel(
    float* __restrict__ q, float* __restrict__ k,
    const float* __restrict__ cos_t, const float* __restrict__ sin_t) {
  int idx = blockIdx.x * blockDim.x + threadIdx.x;
  int d = idx & 31;
  int rest = idx >> 5;
  int head = rest % (HH + HKVN);
  int bs = rest / (HH + HKVN);
  int s = bs % SS;
  float c = cos_t[s * HDIM + d];
  float sn = sin_t[s * HDIM + d];
  float* ptr;
  if (head < HH)
    ptr = q + ((size_t)bs * HH + head) * HDIM;
  else
    ptr = k + ((size_t)bs * HKVN + (head - HH)) * HDIM;
  float x1 = ptr[d];
  float x2 = ptr[d + 32];
  ptr[d] = x1 * c - x2 * sn;
  ptr[d + 32] = x2 * c + x1 * sn;
}

// ---------------- Attention: key-parallel tiles, online softmax ----------
// Block = (b, hk, i): 4 waves = the 4 q-heads sharing kv-head hk (L1 reuse of
// K/V tiles, uniform tile count per block). Per tile of 64 keys: lane=key for
// QK^T (Q in regs, K gathered), one wave-max per TILE, then lane=dim for PV
// with coalesced V loads and shfl-broadcast p. fp32 throughout.
__global__ __launch_bounds__(256) void attn_kernel(
    const float* __restrict__ Q, const float* __restrict__ K,
    const float* __restrict__ V, float* __restrict__ O) {
  int wid = threadIdx.x >> 6;
  int lane = threadIdx.x & 63;
  int i = blockIdx.x & (SS - 1);
  int bhk = blockIdx.x >> 11;  // SS = 2048 = 2^11
  int hk = bhk & (HKVN - 1);
  int b = bhk >> 2;
  int h = hk * (HH / HKVN) + wid;
  const float scale = 0.125f;  // 1/sqrt(64)

  const float* qp = Q + (((size_t)b * SS + i) * HH + h) * HDIM;
  float4 qreg[16];
#pragma unroll
  for (int c = 0; c < 16; c++) qreg[c] = ((const float4*)qp)[c];

  int jstart = i - (WND - 1);
  if (jstart < 0) jstart = 0;
  int t0 = jstart & ~63;

  float m = -INFINITY, l = 0.f, acc = 0.f;
  const float* Kb = K + ((size_t)b * SS * HKVN + hk) * HDIM;
  const float* Vb = V + ((size_t)b * SS * HKVN + hk) * HDIM;

  for (int t = t0; t <= i; t += 64) {
    int j = t + lane;
    bool valid = (j >= jstart) & (j <= i);
    int jc = valid ? j : i;
    const float4* kr = (const float4*)(Kb + (size_t)jc * (HKVN * HDIM));
    float s = 0.f;
#pragma unroll
    for (int c = 0; c < 16; c++) {
      float4 kv = kr[c];
      s += qreg[c].x * kv.x + qreg[c].y * kv.y + qreg[c].z * kv.z +
           qreg[c].w * kv.w;
    }
    s *= scale;
    if (!valid) s = -INFINITY;
    // tile max across 64 lanes
    float mt = s;
#pragma unroll
    for (int o = 32; o > 0; o >>= 1) mt = fmaxf(mt, __shfl_xor(mt, o, 64));
    float mn = fmaxf(m, mt);
    float corr = __expf(m - mn);  // first tile: exp(-inf)=0
    float p = __expf(s - mn);     // invalid lanes -> 0
    l = l * corr + p;
    acc *= corr;
    // PV: lane = output dim now; coalesced V loads, p broadcast via shfl
    const float* vcol = Vb + (size_t)t * (HKVN * HDIM) + lane;
#pragma unroll 16
    for (int jj = 0; jj < 64; jj++) {
      float pj = __shfl(p, jj, 64);
      acc = fmaf(pj, vcol[(size_t)jj * (HKVN * HDIM)], acc);
    }
    m = mn;
  }
  // total l across lanes (corr factors were wave-uniform)
  float lt = l;
#pragma unroll
  for (int o = 32; o > 0; o >>= 1) lt += __shfl_xor(lt, o, 64);
  O[(((size_t)b * SS + i) * HH + h) * HDIM + lane] = acc / lt;
}

extern "C" void kernel_launch(void* const* d_in, const int* in_sizes, int n_in,
                              void* d_out, int out_size, void* d_ws,
                              size_t ws_size, hipStream_t stream) {
  const float* hidden = (const float*)d_in[0];
  const float* cos_t = (const float*)d_in[1];
  const float* sin_t = (const float*)d_in[2];
  const float* wq = (const float*)d_in[3];
  const float* bq = (const float*)d_in[4];
  const float* wk = (const float*)d_in[5];
  const float* bk = (const float*)d_in[6];
  const float* wv = (const float*)d_in[7];
  const float* bv = (const float*)d_in[8];
  const float* wo = (const float*)d_in[9];
  const float* ln1 = (const float*)d_in[10];
  const float* ln2 = (const float*)d_in[11];
  const float* wg = (const float*)d_in[12];
  const float* wu = (const float*)d_in[13];
  const float* wd = (const float*)d_in[14];
  float* out = (float*)d_out;
  float* ws = (float*)d_ws;

  const int M = BB * SS;  // 4096 rows
  float* A_norm = ws;                         // [M, D]
  float* Qb = A_norm + (size_t)M * DD;        // [B,S,H,HD]
  float* Kb = Qb + (size_t)M * DD;            // [B,S,HKV,HD]
  float* Vb = Kb + (size_t)M * HKVN * HDIM;   // [B,S,HKV,HD]
  float* CTX = Vb + (size_t)M * HKVN * HDIM;  // [M, D]
  float* ACT = CTX + (size_t)M * DD;          // [M, FF]
  float* HATT = out;  // residual2 lives in d_out

  rmsnorm_kernel<<<M, 256, 0, stream>>>(hidden, ln1, A_norm, DD);
  gemm64<<<dim3((HH * HDIM) / 64, M / 64), 256, 0, stream>>>(
      A_norm, wq, bq, nullptr, Qb, M, HH * HDIM, DD);
  gemm64<<<dim3((HKVN * HDIM) / 64, M / 64), 256, 0, stream>>>(
      A_norm, wk, bk, nullptr, Kb, M, HKVN * HDIM, DD);
  gemm64<<<dim3((HKVN * HDIM) / 64, M / 64), 256, 0, stream>>>(
      A_norm, wv, bv, nullptr, Vb, M, HKVN * HDIM, DD);
  rope_kernel<<<(BB * SS * (HH + HKVN) * 32) / 256, 256, 0, stream>>>(
      Qb, Kb, cos_t, sin_t);
  attn_kernel<<<BB * HKVN * SS, 256, 0, stream>>>(Qb, Kb, Vb, CTX);
  gemm64<<<dim3(DD / 64, M / 64), 256, 0, stream>>>(CTX, wo, nullptr, hidden,
                                                    HATT, M, DD, DD);
  rmsnorm_kernel<<<M, 256, 0, stream>>>(HATT, ln2, A_norm, DD);
  gateup_kernel<<<dim3(FFD / 64, M / 64), 256, 0, stream>>>(A_norm, wg, wu, ACT,
                                                            M, FFD, DD);
  gemm64<<<dim3(DD / 64, M / 64), 256, 0, stream>>>(ACT, wd, nullptr, HATT, out,
                                                    M, DD, FFD);
}

// Round 3
// 2156.539 us; speedup vs baseline: 2.6071x; 1.9193x over previous
//
#include <hip/hip_runtime.h>
#include <hip/hip_bf16.h>
#include <hip/hip_fp16.h>
#include <math.h>

// Qwen2 decoder layer, MI355X. Round 3: f16 MFMA GEMMs (m97 structure),
// attention unchanged (next round's target).
// B=2 S=2048 D=1024 H=16 HKV=4 HD=64 FF=4096 WINDOW=1024
#define BB 2
#define SS 2048
#define DD 1024
#define HH 16
#define HKVN 4
#define HDIM 64
#define FFD 4096
#define WND 1024
#define EPSF 1e-6f

typedef _Float16 f16;
typedef _Float16 half8 __attribute__((ext_vector_type(8)));
typedef float f32x4 __attribute__((ext_vector_type(4)));
typedef unsigned int u32;

// ---------------- Weight transpose+cast: Wt[N][K] f16 = W[K][N] f32 --------
__global__ __launch_bounds__(256) void transpose_cast_kernel(
    const float* __restrict__ W, f16* __restrict__ Wt, int K, int N) {
  __shared__ float tile[64][65];
  int k0 = blockIdx.y * 64, n0 = blockIdx.x * 64;
  int tx = threadIdx.x & 63, tr = threadIdx.x >> 6;
#pragma unroll
  for (int i = 0; i < 16; i++) {
    int r = tr + i * 4;
    tile[r][tx] = W[(size_t)(k0 + r) * N + n0 + tx];
  }
  __syncthreads();
#pragma unroll
  for (int i = 0; i < 16; i++) {
    int r = tr + i * 4;  // n-local
    Wt[(size_t)(n0 + r) * K + k0 + tx] = (f16)tile[tx][r];
  }
}

// ---------------- RMSNorm: fp32 in -> f16 out ----------------
__global__ __launch_bounds__(256) void rmsnorm_kernel(
    const float* __restrict__ x, const float* __restrict__ w,
    f16* __restrict__ out, int d) {
  int row = blockIdx.x;
  const float* xr = x + (size_t)row * d;
  float ss = 0.f;
  for (int i = threadIdx.x; i < d; i += blockDim.x) {
    float v = xr[i];
    ss += v * v;
  }
  __shared__ float red[8];
  for (int o = 32; o > 0; o >>= 1) ss += __shfl_down(ss, o, 64);
  int wid = threadIdx.x >> 6, lane = threadIdx.x & 63;
  if (lane == 0) red[wid] = ss;
  __syncthreads();
  if (threadIdx.x == 0) {
    float t = 0.f;
    int nw = blockDim.x >> 6;
    for (int i = 0; i < nw; i++) t += red[i];
    red[0] = rsqrtf(t / (float)d + EPSF);
  }
  __syncthreads();
  float rs = red[0];
  f16* orow = out + (size_t)row * d;
  for (int i = threadIdx.x; i < d; i += blockDim.x) {
    orow[i] = (f16)(xr[i] * rs * w[i]);
  }
}

// ---------------- f16 MFMA GEMM (m97 structure) ----------------
// C[M][N] = A[M][K] @ B  with B given transposed: Bt[N][K] (f16).
// 128x128 tile, BK=32, 4 waves x (64x64), v_mfma_f32_16x16x32_f16.
// LDS: linear dest for global_load_lds, chunk-XOR swizzle via pre-swizzled
// global source; ds_read_b128 frag reads (2-way bank conflicts only).
// DUAL: second Bt2 operand, epilogue silu(C1)*C2 -> f16 Ch.
// else: C1 (+bias) (+resid) -> fp32 Cf.
template <bool DUAL>
__global__ __launch_bounds__(256) void mfma_gemm(
    const f16* __restrict__ A, const f16* __restrict__ Bt,
    const f16* __restrict__ Bt2, const float* __restrict__ bias,
    const float* __restrict__ resid, float* __restrict__ Cf,
    f16* __restrict__ Ch, int M, int N, int K) {
  constexpr int NB = DUAL ? 3 : 2;           // tiles per buffer (A,B[,B2])
  constexpr int BUFB = NB * 8192;            // bytes per double-buffer half
  __shared__ __align__(16) char smem[2 * BUFB];
  const int tid = threadIdx.x;
  const int lane = tid & 63;
  const int wid = tid >> 6;
  const int wr = wid >> 1, wc = wid & 1;
  const int row0 = blockIdx.y * 128, col0 = blockIdx.x * 128;

  f32x4 acc[4][4];
  f32x4 acc2[DUAL ? 4 : 1][DUAL ? 4 : 1];
#pragma unroll
  for (int m = 0; m < 4; m++)
#pragma unroll
    for (int n = 0; n < 4; n++) {
      acc[m][n] = (f32x4){0.f, 0.f, 0.f, 0.f};
      if constexpr (DUAL) acc2[m][n] = (f32x4){0.f, 0.f, 0.f, 0.f};
    }

  // stage one K-step tile set into buffer `buf` for k-offset k0
  auto stage = [&](int buf, int k0) {
    char* base = smem + buf * BUFB;
#pragma unroll
    for (int q = 0; q < 2; q++) {
      int s = wid * 128 + q * 64 + lane;      // 16B slot index
      int r = s >> 2;                          // tile row (0..127)
      int cg = (s & 3) ^ ((r >> 1) & 3);       // global k-chunk (swizzled src)
      size_t goff = (size_t)r * K + k0 + cg * 8;
      u32 ldsb = (u32)((wid * 2 + q) * 1024);  // wave-uniform base, +lane*16 HW
      __builtin_amdgcn_global_load_lds(
          (const __attribute__((address_space(1))) u32*)(A + (size_t)row0 * K + goff),
          (__attribute__((address_space(3))) u32*)(base + ldsb), 16, 0, 0);
      __builtin_amdgcn_global_load_lds(
          (const __attribute__((address_space(1))) u32*)(Bt + (size_t)col0 * K + goff),
          (__attribute__((address_space(3))) u32*)(base + 8192 + ldsb), 16, 0, 0);
      if constexpr (DUAL) {
        __builtin_amdgcn_global_load_lds(
            (const __attribute__((address_space(1))) u32*)(Bt2 + (size_t)col0 * K + goff),
            (__attribute__((address_space(3))) u32*)(base + 16384 + ldsb), 16, 0, 0);
      }
    }
  };
  // physical byte offset of (row r, k-chunk g) in a staged tile
  auto off = [&](int r, int g) -> int {
    return r * 64 + ((g ^ ((r >> 1) & 3)) << 4);
  };

  const int nt = K / 32;
  stage(0, 0);
  __syncthreads();  // compiler emits vmcnt(0) drain before barrier
  int cur = 0;
  const int g = lane >> 4, l15 = lane & 15;
  for (int t = 0; t < nt; t++) {
    if (t + 1 < nt) stage(cur ^ 1, (t + 1) * 32);
    const char* base = smem + cur * BUFB;
    half8 af[4], bf[4], uf[DUAL ? 4 : 1];
#pragma unroll
    for (int m = 0; m < 4; m++) {
      int r = wr * 64 + m * 16 + l15;
      af[m] = *(const half8*)(base + off(r, g));
    }
#pragma unroll
    for (int n = 0; n < 4; n++) {
      int c = wc * 64 + n * 16 + l15;
      bf[n] = *(const half8*)(base + 8192 + off(c, g));
      if constexpr (DUAL) uf[n] = *(const half8*)(base + 16384 + off(c, g));
    }
#pragma unroll
    for (int m = 0; m < 4; m++)
#pragma unroll
      for (int n = 0; n < 4; n++) {
        acc[m][n] =
            __builtin_amdgcn_mfma_f32_16x16x32_f16(af[m], bf[n], acc[m][n], 0, 0, 0);
        if constexpr (DUAL)
          acc2[m][n] = __builtin_amdgcn_mfma_f32_16x16x32_f16(af[m], uf[n],
                                                              acc2[m][n], 0, 0, 0);
      }
    __syncthreads();
    cur ^= 1;
  }

  // epilogue: C layout col=lane&15, row=(lane>>4)*4+reg
#pragma unroll
  for (int m = 0; m < 4; m++) {
#pragma unroll
    for (int n = 0; n < 4; n++) {
#pragma unroll
      for (int v = 0; v < 4; v++) {
        int r = row0 + wr * 64 + m * 16 + (lane >> 4) * 4 + v;
        int c = col0 + wc * 64 + n * 16 + (lane & 15);
        if constexpr (DUAL) {
          float gg = acc[m][n][v];
          float uu = acc2[m][n][v];
          float sv = gg / (1.f + __expf(-gg));
          Ch[(size_t)r * N + c] = (f16)(sv * uu);
        } else {
          float vv = acc[m][n][v];
          if (bias) vv += bias[c];
          if (resid) vv += resid[(size_t)r * N + c];
          Cf[(size_t)r * N + c] = vv;
        }
      }
    }
  }
}

// ---------------- RoPE (in-place on Q and K, fp32) ----------------
__global__ __launch_bounds__(256) void rope_kernel(
    float* __restrict__ q, float* __restrict__ k,
    const float* __restrict__ cos_t, const float* __restrict__ sin_t) {
  int idx = blockIdx.x * blockDim.x + threadIdx.x;
  int d = idx & 31;
  int rest = idx >> 5;
  int head = rest % (HH + HKVN);
  int bs = rest / (HH + HKVN);
  int s = bs % SS;
  float c = cos_t[s * HDIM + d];
  float sn = sin_t[s * HDIM + d];
  float* ptr;
  if (head < HH)
    ptr = q + ((size_t)bs * HH + head) * HDIM;
  else
    ptr = k + ((size_t)bs * HKVN + (head - HH)) * HDIM;
  float x1 = ptr[d];
  float x2 = ptr[d + 32];
  ptr[d] = x1 * c - x2 * sn;
  ptr[d + 32] = x2 * c + x1 * sn;
}

// ---------------- Attention (unchanged R2 structure, f16 output) ----------
__global__ __launch_bounds__(256) void attn_kernel(
    const float* __restrict__ Q, const float* __restrict__ K,
    const float* __restrict__ V, f16* __restrict__ O) {
  int wid = threadIdx.x >> 6;
  int lane = threadIdx.x & 63;
  int i = blockIdx.x & (SS - 1);
  int bhk = blockIdx.x >> 11;
  int hk = bhk & (HKVN - 1);
  int b = bhk >> 2;
  int h = hk * (HH / HKVN) + wid;
  const float scale = 0.125f;

  const float* qp = Q + (((size_t)b * SS + i) * HH + h) * HDIM;
  float4 qreg[16];
#pragma unroll
  for (int c = 0; c < 16; c++) qreg[c] = ((const float4*)qp)[c];

  int jstart = i - (WND - 1);
  if (jstart < 0) jstart = 0;
  int t0 = jstart & ~63;

  float m = -INFINITY, l = 0.f, acc = 0.f;
  const float* Kb = K + ((size_t)b * SS * HKVN + hk) * HDIM;
  const float* Vb = V + ((size_t)b * SS * HKVN + hk) * HDIM;

  for (int t = t0; t <= i; t += 64) {
    int j = t + lane;
    bool valid = (j >= jstart) & (j <= i);
    int jc = valid ? j : i;
    const float4* kr = (const float4*)(Kb + (size_t)jc * (HKVN * HDIM));
    float s = 0.f;
#pragma unroll
    for (int c = 0; c < 16; c++) {
      float4 kv = kr[c];
      s += qreg[c].x * kv.x + qreg[c].y * kv.y + qreg[c].z * kv.z +
           qreg[c].w * kv.w;
    }
    s *= scale;
    if (!valid) s = -INFINITY;
    float mt = s;
#pragma unroll
    for (int o = 32; o > 0; o >>= 1) mt = fmaxf(mt, __shfl_xor(mt, o, 64));
    float mn = fmaxf(m, mt);
    float corr = __expf(m - mn);
    float p = __expf(s - mn);
    l = l * corr + p;
    acc *= corr;
    const float* vcol = Vb + (size_t)t * (HKVN * HDIM) + lane;
#pragma unroll 16
    for (int jj = 0; jj < 64; jj++) {
      float pj = __shfl(p, jj, 64);
      acc = fmaf(pj, vcol[(size_t)jj * (HKVN * HDIM)], acc);
    }
    m = mn;
  }
  float lt = l;
#pragma unroll
  for (int o = 32; o > 0; o >>= 1) lt += __shfl_xor(lt, o, 64);
  O[(((size_t)b * SS + i) * HH + h) * HDIM + lane] = (f16)(acc / lt);
}

extern "C" void kernel_launch(void* const* d_in, const int* in_sizes, int n_in,
                              void* d_out, int out_size, void* d_ws,
                              size_t ws_size, hipStream_t stream) {
  const float* hidden = (const float*)d_in[0];
  const float* cos_t = (const float*)d_in[1];
  const float* sin_t = (const float*)d_in[2];
  const float* wq = (const float*)d_in[3];
  const float* bq = (const float*)d_in[4];
  const float* wk = (const float*)d_in[5];
  const float* bk = (const float*)d_in[6];
  const float* wv = (const float*)d_in[7];
  const float* bv = (const float*)d_in[8];
  const float* wo = (const float*)d_in[9];
  const float* ln1 = (const float*)d_in[10];
  const float* ln2 = (const float*)d_in[11];
  const float* wg = (const float*)d_in[12];
  const float* wu = (const float*)d_in[13];
  const float* wd = (const float*)d_in[14];
  float* out = (float*)d_out;
  char* ws = (char*)d_ws;

  const int M = BB * SS;  // 4096

  // workspace layout (bytes)
  f16* wqT = (f16*)ws;                          // [1024][1024] 2MB
  f16* wkT = (f16*)(ws + (2u << 20));           // [256][1024] 0.5MB
  f16* wvT = (f16*)(ws + (2560u << 10));        // 0.5MB
  f16* woT = (f16*)(ws + (3u << 20));           // 2MB
  f16* wgT = (f16*)(ws + (5u << 20));           // [4096][1024] 8MB
  f16* wuT = (f16*)(ws + (13u << 20));          // 8MB
  f16* wdT = (f16*)(ws + (21u << 20));          // [1024][4096] 8MB
  f16* Anh = (f16*)(ws + (29u << 20));          // [M][1024] f16 8MB
  float* Qb = (float*)(ws + (37u << 20));       // [M][1024] 16MB
  float* Kb = (float*)(ws + (53u << 20));       // [M][256] 4MB
  float* Vb = (float*)(ws + (57u << 20));       // [M][256] 4MB
  f16* CTXh = (f16*)(ws + (61u << 20));         // [M][1024] 8MB
  f16* ACTh = (f16*)(ws + (69u << 20));         // [M][4096] 32MB -> ends 101MB

  // 1) transpose+cast weights to f16 [N][K]
  transpose_cast_kernel<<<dim3(DD / 64, DD / 64), 256, 0, stream>>>(wq, wqT, DD, DD);
  transpose_cast_kernel<<<dim3(4, DD / 64), 256, 0, stream>>>(wk, wkT, DD, 256);
  transpose_cast_kernel<<<dim3(4, DD / 64), 256, 0, stream>>>(wv, wvT, DD, 256);
  transpose_cast_kernel<<<dim3(DD / 64, DD / 64), 256, 0, stream>>>(wo, woT, DD, DD);
  transpose_cast_kernel<<<dim3(FFD / 64, DD / 64), 256, 0, stream>>>(wg, wgT, DD, FFD);
  transpose_cast_kernel<<<dim3(FFD / 64, DD / 64), 256, 0, stream>>>(wu, wuT, DD, FFD);
  transpose_cast_kernel<<<dim3(DD / 64, FFD / 64), 256, 0, stream>>>(wd, wdT, FFD, DD);

  // 2) RMSNorm 1 -> f16
  rmsnorm_kernel<<<M, 256, 0, stream>>>(hidden, ln1, Anh, DD);
  // 3) QKV projections (f16 MFMA, fp32 out)
  mfma_gemm<false><<<dim3((HH * HDIM) / 128, M / 128), 256, 0, stream>>>(
      Anh, wqT, nullptr, bq, nullptr, Qb, nullptr, M, HH * HDIM, DD);
  mfma_gemm<false><<<dim3((HKVN * HDIM) / 128, M / 128), 256, 0, stream>>>(
      Anh, wkT, nullptr, bk, nullptr, Kb, nullptr, M, HKVN * HDIM, DD);
  mfma_gemm<false><<<dim3((HKVN * HDIM) / 128, M / 128), 256, 0, stream>>>(
      Anh, wvT, nullptr, bv, nullptr, Vb, nullptr, M, HKVN * HDIM, DD);
  // 4) RoPE
  rope_kernel<<<(BB * SS * (HH + HKVN) * 32) / 256, 256, 0, stream>>>(
      Qb, Kb, cos_t, sin_t);
  // 5) Attention -> f16 CTX
  attn_kernel<<<BB * HKVN * SS, 256, 0, stream>>>(Qb, Kb, Vb, CTXh);
  // 6) Output projection + residual -> d_out (fp32)
  mfma_gemm<false><<<dim3(DD / 128, M / 128), 256, 0, stream>>>(
      CTXh, woT, nullptr, nullptr, hidden, out, nullptr, M, DD, DD);
  // 7) RMSNorm 2 -> f16
  rmsnorm_kernel<<<M, 256, 0, stream>>>(out, ln2, Anh, DD);
  // 8) MLP gate/up dual GEMM + SiLU*up -> f16 ACT
  mfma_gemm<true><<<dim3(FFD / 128, M / 128), 256, 0, stream>>>(
      Anh, wgT, wuT, nullptr, nullptr, nullptr, ACTh, M, FFD, DD);
  // 9) MLP down + residual2 -> d_out
  mfma_gemm<false><<<dim3(DD / 128, M / 128), 256, 0, stream>>>(
      ACTh, wdT, nullptr, nullptr, out, out, nullptr, M, DD, FFD);
}

// Round 4
// 399.274 us; speedup vs baseline: 14.0812x; 5.4012x over previous
//
#include <hip/hip_runtime.h>
#include <hip/hip_bf16.h>
#include <hip/hip_fp16.h>
#include <math.h>

// Qwen2 decoder layer, MI355X. Round 4: MFMA flash attention + f16 MFMA GEMMs.
// B=2 S=2048 D=1024 H=16 HKV=4 HD=64 FF=4096 WINDOW=1024
#define BB 2
#define SS 2048
#define DD 1024
#define HH 16
#define HKVN 4
#define HDIM 64
#define FFD 4096
#define WND 1024
#define EPSF 1e-6f

typedef _Float16 f16;
typedef _Float16 half8 __attribute__((ext_vector_type(8)));
typedef float f32x4 __attribute__((ext_vector_type(4)));
typedef unsigned int u32;

static __device__ inline u32 pack2(float a, float b) {
  unsigned short ua = __builtin_bit_cast(unsigned short, (f16)a);
  unsigned short ub = __builtin_bit_cast(unsigned short, (f16)b);
  return (u32)ua | ((u32)ub << 16);
}

// ---------------- Weight transpose+cast: Wt[N][K] f16 = W[K][N] f32 --------
__global__ __launch_bounds__(256) void transpose_cast_kernel(
    const float* __restrict__ W, f16* __restrict__ Wt, int K, int N) {
  __shared__ float tile[64][65];
  int k0 = blockIdx.y * 64, n0 = blockIdx.x * 64;
  int tx = threadIdx.x & 63, tr = threadIdx.x >> 6;
#pragma unroll
  for (int i = 0; i < 16; i++) {
    int r = tr + i * 4;
    tile[r][tx] = W[(size_t)(k0 + r) * N + n0 + tx];
  }
  __syncthreads();
#pragma unroll
  for (int i = 0; i < 16; i++) {
    int r = tr + i * 4;  // n-local
    Wt[(size_t)(n0 + r) * K + k0 + tx] = (f16)tile[tx][r];
  }
}

// ---------------- RMSNorm: fp32 in -> f16 out ----------------
__global__ __launch_bounds__(256) void rmsnorm_kernel(
    const float* __restrict__ x, const float* __restrict__ w,
    f16* __restrict__ out, int d) {
  int row = blockIdx.x;
  const float* xr = x + (size_t)row * d;
  float ss = 0.f;
  for (int i = threadIdx.x; i < d; i += blockDim.x) {
    float v = xr[i];
    ss += v * v;
  }
  __shared__ float red[8];
  for (int o = 32; o > 0; o >>= 1) ss += __shfl_down(ss, o, 64);
  int wid = threadIdx.x >> 6, lane = threadIdx.x & 63;
  if (lane == 0) red[wid] = ss;
  __syncthreads();
  if (threadIdx.x == 0) {
    float t = 0.f;
    int nw = blockDim.x >> 6;
    for (int i = 0; i < nw; i++) t += red[i];
    red[0] = rsqrtf(t / (float)d + EPSF);
  }
  __syncthreads();
  float rs = red[0];
  f16* orow = out + (size_t)row * d;
  for (int i = threadIdx.x; i < d; i += blockDim.x) {
    orow[i] = (f16)(xr[i] * rs * w[i]);
  }
}

// ---------------- f16 MFMA GEMM (m97 structure) ----------------
template <bool DUAL>
__global__ __launch_bounds__(256) void mfma_gemm(
    const f16* __restrict__ A, const f16* __restrict__ Bt,
    const f16* __restrict__ Bt2, const float* __restrict__ bias,
    const float* __restrict__ resid, float* __restrict__ Cf,
    f16* __restrict__ Ch, int M, int N, int K) {
  constexpr int NB = DUAL ? 3 : 2;
  constexpr int BUFB = NB * 8192;
  __shared__ __align__(16) char smem[2 * BUFB];
  const int tid = threadIdx.x;
  const int lane = tid & 63;
  const int wid = tid >> 6;
  const int wr = wid >> 1, wc = wid & 1;
  const int row0 = blockIdx.y * 128, col0 = blockIdx.x * 128;

  f32x4 acc[4][4];
  f32x4 acc2[DUAL ? 4 : 1][DUAL ? 4 : 1];
#pragma unroll
  for (int m = 0; m < 4; m++)
#pragma unroll
    for (int n = 0; n < 4; n++) {
      acc[m][n] = (f32x4){0.f, 0.f, 0.f, 0.f};
      if constexpr (DUAL) acc2[m][n] = (f32x4){0.f, 0.f, 0.f, 0.f};
    }

  auto stage = [&](int buf, int k0) {
    char* base = smem + buf * BUFB;
#pragma unroll
    for (int q = 0; q < 2; q++) {
      int s = wid * 128 + q * 64 + lane;
      int r = s >> 2;
      int cg = (s & 3) ^ ((r >> 1) & 3);
      size_t goff = (size_t)r * K + k0 + cg * 8;
      u32 ldsb = (u32)((wid * 2 + q) * 1024);
      __builtin_amdgcn_global_load_lds(
          (const __attribute__((address_space(1))) u32*)(A + (size_t)row0 * K + goff),
          (__attribute__((address_space(3))) u32*)(base + ldsb), 16, 0, 0);
      __builtin_amdgcn_global_load_lds(
          (const __attribute__((address_space(1))) u32*)(Bt + (size_t)col0 * K + goff),
          (__attribute__((address_space(3))) u32*)(base + 8192 + ldsb), 16, 0, 0);
      if constexpr (DUAL) {
        __builtin_amdgcn_global_load_lds(
            (const __attribute__((address_space(1))) u32*)(Bt2 + (size_t)col0 * K + goff),
            (__attribute__((address_space(3))) u32*)(base + 16384 + ldsb), 16, 0, 0);
      }
    }
  };
  auto off = [&](int r, int g) -> int {
    return r * 64 + ((g ^ ((r >> 1) & 3)) << 4);
  };

  const int nt = K / 32;
  stage(0, 0);
  __syncthreads();
  int cur = 0;
  const int g = lane >> 4, l15 = lane & 15;
  for (int t = 0; t < nt; t++) {
    if (t + 1 < nt) stage(cur ^ 1, (t + 1) * 32);
    const char* base = smem + cur * BUFB;
    half8 af[4], bf[4], uf[DUAL ? 4 : 1];
#pragma unroll
    for (int m = 0; m < 4; m++) {
      int r = wr * 64 + m * 16 + l15;
      af[m] = *(const half8*)(base + off(r, g));
    }
#pragma unroll
    for (int n = 0; n < 4; n++) {
      int c = wc * 64 + n * 16 + l15;
      bf[n] = *(const half8*)(base + 8192 + off(c, g));
      if constexpr (DUAL) uf[n] = *(const half8*)(base + 16384 + off(c, g));
    }
#pragma unroll
    for (int m = 0; m < 4; m++)
#pragma unroll
      for (int n = 0; n < 4; n++) {
        acc[m][n] =
            __builtin_amdgcn_mfma_f32_16x16x32_f16(af[m], bf[n], acc[m][n], 0, 0, 0);
        if constexpr (DUAL)
          acc2[m][n] = __builtin_amdgcn_mfma_f32_16x16x32_f16(af[m], uf[n],
                                                              acc2[m][n], 0, 0, 0);
      }
    __syncthreads();
    cur ^= 1;
  }

#pragma unroll
  for (int m = 0; m < 4; m++) {
#pragma unroll
    for (int n = 0; n < 4; n++) {
#pragma unroll
      for (int v = 0; v < 4; v++) {
        int r = row0 + wr * 64 + m * 16 + (lane >> 4) * 4 + v;
        int c = col0 + wc * 64 + n * 16 + (lane & 15);
        if constexpr (DUAL) {
          float gg = acc[m][n][v];
          float uu = acc2[m][n][v];
          float sv = gg / (1.f + __expf(-gg));
          Ch[(size_t)r * N + c] = (f16)(sv * uu);
        } else {
          float vv = acc[m][n][v];
          if (bias) vv += bias[c];
          if (resid) vv += resid[(size_t)r * N + c];
          Cf[(size_t)r * N + c] = vv;
        }
      }
    }
  }
}

// ---------------- RoPE + cast: fp32 Qb/Kb -> f16 Qh (pre-scaled), Kh --------
__global__ __launch_bounds__(256) void rope_cast_kernel(
    const float* __restrict__ Qb, const float* __restrict__ Kb,
    const float* __restrict__ cos_t, const float* __restrict__ sin_t,
    f16* __restrict__ Qh, f16* __restrict__ Kh) {
  int idx = blockIdx.x * blockDim.x + threadIdx.x;
  int d = idx & 31;
  int rest = idx >> 5;
  int head = rest % (HH + HKVN);
  int bs = rest / (HH + HKVN);
  int s = bs % SS;
  float c = cos_t[s * HDIM + d];
  float sn = sin_t[s * HDIM + d];
  if (head < HH) {
    const float* base = Qb + ((size_t)bs * HH + head) * HDIM;
    float x1 = base[d], x2 = base[d + 32];
    f16* ob = Qh + ((size_t)bs * HH + head) * HDIM;
    ob[d] = (f16)((x1 * c - x2 * sn) * 0.125f);
    ob[d + 32] = (f16)((x2 * c + x1 * sn) * 0.125f);
  } else {
    int hk = head - HH;
    const float* base = Kb + ((size_t)bs * HKVN + hk) * HDIM;
    float x1 = base[d], x2 = base[d + 32];
    f16* ob = Kh + ((size_t)bs * HKVN + hk) * HDIM;
    ob[d] = (f16)(x1 * c - x2 * sn);
    ob[d + 32] = (f16)(x2 * c + x1 * sn);
  }
}

// ---------------- V transpose+cast: Vb fp32 [b][s][hk][64] -> Vt f16
// [(b*4+hk)][d][S] ----------------
__global__ __launch_bounds__(256) void vtrans_kernel(const float* __restrict__ Vb,
                                                     f16* __restrict__ Vt) {
  __shared__ float tile[64][65];
  int st = blockIdx.x & 31;
  int hk = (blockIdx.x >> 5) & 3;
  int b = blockIdx.x >> 7;
  int s0 = st * 64;
  int tid = threadIdx.x;
  int r = tid >> 2, cg = tid & 3;
#pragma unroll
  for (int i = 0; i < 4; i++) {
    int c0 = cg * 16 + i * 4;
    float4 vv = *(const float4*)(Vb + ((size_t)(b * SS + s0 + r) * HKVN + hk) * HDIM + c0);
    tile[r][c0 + 0] = vv.x;
    tile[r][c0 + 1] = vv.y;
    tile[r][c0 + 2] = vv.z;
    tile[r][c0 + 3] = vv.w;
  }
  __syncthreads();
  int dd = tid >> 2, sg = tid & 3;
#pragma unroll
  for (int i = 0; i < 4; i++) {
    int c0 = sg * 16 + i * 4;
    u32 w0 = pack2(tile[c0 + 0][dd], tile[c0 + 1][dd]);
    u32 w1 = pack2(tile[c0 + 2][dd], tile[c0 + 3][dd]);
    *(int2*)(Vt + ((size_t)(b * HKVN + hk) * HDIM + dd) * SS + s0 + c0) =
        make_int2((int)w0, (int)w1);
  }
}

// ---------------- Flash attention, MFMA 16x16x32 f16 ----------------
// Block = (b, hk, 32-row q-tile); 4 waves = 4 q-heads of the GQA group.
// K/V staged in LDS (double-buffered, 64-key tiles); swapped QK^T -> C[key][q];
// P via per-wave LDS; PV from V^T tiles. Online softmax in fp32.
__global__ __launch_bounds__(256) void attn_kernel(
    const f16* __restrict__ Qh, const f16* __restrict__ Kh,
    const f16* __restrict__ Vt, f16* __restrict__ O) {
  __shared__ __align__(16) char smem[2 * 16384 + 4 * 4608];
  const int tid = threadIdx.x;
  const int lane = tid & 63;
  const int wid = tid >> 6;
  const int l15 = lane & 15;
  const int g = lane >> 4;
  int qt = blockIdx.x & 63;
  int hk = (blockIdx.x >> 6) & 3;
  int b = blockIdx.x >> 8;
  int s0 = qt * 32;
  int h = hk * 4 + wid;

  // Q fragments (B-operand): qf[n][kk]; lane holds q=n*16+l15, d=kk*32+g*8..+7
  half8 qf[2][2];
#pragma unroll
  for (int n = 0; n < 2; n++) {
    int q = s0 + n * 16 + l15;
    const f16* qp = Qh + (((size_t)b * SS + q) * HH + h) * HDIM;
#pragma unroll
    for (int kk = 0; kk < 2; kk++) qf[n][kk] = *(const half8*)(qp + kk * 32 + g * 8);
  }

  const int tb = (s0 >= WND) ? ((s0 - (WND - 1)) >> 6) : 0;
  const int te = (s0 + 31) >> 6;

  f32x4 acc_o[2][4];
#pragma unroll
  for (int m2 = 0; m2 < 2; m2++)
#pragma unroll
    for (int n = 0; n < 4; n++) acc_o[m2][n] = (f32x4){0.f, 0.f, 0.f, 0.f};
  float mrun[2] = {-1e30f, -1e30f};
  float lrun[2] = {0.f, 0.f};

  char* pw = smem + 32768 + wid * 4608;  // per-wave P tile [32][72] f16

  // stage tile tt into buffer buf: K [64 key][64 d], V^T [64 d][64 key], f16,
  // linear LDS dest + XOR-swizzled global source (chunk ^= row&7)
  auto stage = [&](int buf, int tt) {
    int jt0 = tt * 64;
    char* kbase = smem + buf * 16384;
#pragma unroll
    for (int q2 = 0; q2 < 2; q2++) {
      int slot = (wid * 2 + q2) * 64 + lane;
      int r = slot >> 3, c = slot & 7;
      int cc = c ^ (r & 7);
      u32 ldsb = (u32)((wid * 2 + q2) * 1024);
      const f16* gk =
          Kh + ((size_t)(b * SS + jt0 + r) * HKVN + hk) * HDIM + cc * 8;
      __builtin_amdgcn_global_load_lds(
          (const __attribute__((address_space(1))) u32*)gk,
          (__attribute__((address_space(3))) u32*)(kbase + ldsb), 16, 0, 0);
      const f16* gv =
          Vt + ((size_t)(b * HKVN + hk) * HDIM + r) * SS + jt0 + cc * 8;
      __builtin_amdgcn_global_load_lds(
          (const __attribute__((address_space(1))) u32*)gv,
          (__attribute__((address_space(3))) u32*)(kbase + 8192 + ldsb), 16, 0, 0);
    }
  };

  stage(0, tb);
  __syncthreads();
  for (int tt = tb; tt <= te; tt++) {
    int buf = (tt - tb) & 1;
    if (tt < te) stage(buf ^ 1, tt + 1);
    const char* kb = smem + buf * 16384;
    const char* vbp = kb + 8192;
    int jt0 = tt * 64;

    // QK^T (swapped): acc_s[m][n] = C[key m*16..][q n*16..]
    f32x4 acc_s[4][2];
#pragma unroll
    for (int m = 0; m < 4; m++)
#pragma unroll
      for (int n = 0; n < 2; n++) acc_s[m][n] = (f32x4){0.f, 0.f, 0.f, 0.f};
#pragma unroll
    for (int kk = 0; kk < 2; kk++) {
      half8 af[4];
#pragma unroll
      for (int m = 0; m < 4; m++) {
        int key = m * 16 + l15;
        af[m] = *(const half8*)(kb + key * 128 + (((kk * 4 + g) ^ (key & 7)) << 4));
      }
#pragma unroll
      for (int m = 0; m < 4; m++)
#pragma unroll
        for (int n = 0; n < 2; n++)
          acc_s[m][n] = __builtin_amdgcn_mfma_f32_16x16x32_f16(af[m], qf[n][kk],
                                                               acc_s[m][n], 0, 0, 0);
    }

    // mask + tile max (causal + sliding window): valid iff 0 <= q-j < 1024
    float tmax[2] = {-1e38f, -1e38f};
#pragma unroll
    for (int m = 0; m < 4; m++)
#pragma unroll
      for (int n = 0; n < 2; n++)
#pragma unroll
        for (int v = 0; v < 4; v++) {
          int j = jt0 + m * 16 + g * 4 + v;
          int q = s0 + n * 16 + l15;
          float s = acc_s[m][n][v];
          s = ((unsigned)(q - j) < (unsigned)WND) ? s : -1e38f;
          acc_s[m][n][v] = s;
          tmax[n] = fmaxf(tmax[n], s);
        }
#pragma unroll
    for (int n = 0; n < 2; n++) {
      tmax[n] = fmaxf(tmax[n], __shfl_xor(tmax[n], 16, 64));
      tmax[n] = fmaxf(tmax[n], __shfl_xor(tmax[n], 32, 64));
    }
    float corr[2], rs[2];
#pragma unroll
    for (int n = 0; n < 2; n++) {
      float mn = fmaxf(mrun[n], tmax[n]);
      corr[n] = __expf(mrun[n] - mn);
      mrun[n] = mn;
      rs[n] = 0.f;
    }
    // P = exp(s - m), row-sum, write f16 P to per-wave LDS [q][key]
#pragma unroll
    for (int m = 0; m < 4; m++)
#pragma unroll
      for (int n = 0; n < 2; n++) {
        float p0 = __expf(acc_s[m][n][0] - mrun[n]);
        float p1 = __expf(acc_s[m][n][1] - mrun[n]);
        float p2 = __expf(acc_s[m][n][2] - mrun[n]);
        float p3 = __expf(acc_s[m][n][3] - mrun[n]);
        rs[n] += (p0 + p1) + (p2 + p3);
        *(int2*)(pw + (n * 16 + l15) * 144 + (m * 16 + g * 4) * 2) =
            make_int2((int)pack2(p0, p1), (int)pack2(p2, p3));
      }
#pragma unroll
    for (int n = 0; n < 2; n++) {
      rs[n] += __shfl_xor(rs[n], 16, 64);
      rs[n] += __shfl_xor(rs[n], 32, 64);
      lrun[n] = lrun[n] * corr[n] + rs[n];
    }
    // rescale O accumulator (corr broadcast to O-row layout)
#pragma unroll
    for (int m2 = 0; m2 < 2; m2++)
#pragma unroll
      for (int v = 0; v < 4; v++) {
        float cw = __shfl(corr[m2], g * 4 + v, 64);
#pragma unroll
        for (int n = 0; n < 4; n++) acc_o[m2][n][v] *= cw;
      }
    // PV: A = P (from LDS), B = V (from V^T tile)
#pragma unroll
    for (int kk = 0; kk < 2; kk++) {
      half8 ap[2], vf[4];
#pragma unroll
      for (int m2 = 0; m2 < 2; m2++)
        ap[m2] = *(const half8*)(pw + (m2 * 16 + l15) * 144 + (kk * 32 + g * 8) * 2);
#pragma unroll
      for (int n = 0; n < 4; n++) {
        int d = n * 16 + l15;
        vf[n] = *(const half8*)(vbp + d * 128 + (((kk * 4 + g) ^ (d & 7)) << 4));
      }
#pragma unroll
      for (int m2 = 0; m2 < 2; m2++)
#pragma unroll
        for (int n = 0; n < 4; n++)
          acc_o[m2][n] = __builtin_amdgcn_mfma_f32_16x16x32_f16(ap[m2], vf[n],
                                                                acc_o[m2][n], 0, 0, 0);
    }
    __syncthreads();
  }

  // epilogue: divide by l (broadcast to O-row layout), write f16
#pragma unroll
  for (int m2 = 0; m2 < 2; m2++)
#pragma unroll
    for (int v = 0; v < 4; v++) {
      float li = __shfl(lrun[m2], g * 4 + v, 64);
      float inv = 1.f / li;
      int q = s0 + m2 * 16 + g * 4 + v;
#pragma unroll
      for (int n = 0; n < 4; n++) {
        int d = n * 16 + l15;
        O[(((size_t)b * SS + q) * HH + h) * HDIM + d] =
            (f16)(acc_o[m2][n][v] * inv);
      }
    }
}

extern "C" void kernel_launch(void* const* d_in, const int* in_sizes, int n_in,
                              void* d_out, int out_size, void* d_ws,
                              size_t ws_size, hipStream_t stream) {
  const float* hidden = (const float*)d_in[0];
  const float* cos_t = (const float*)d_in[1];
  const float* sin_t = (const float*)d_in[2];
  const float* wq = (const float*)d_in[3];
  const float* bq = (const float*)d_in[4];
  const float* wk = (const float*)d_in[5];
  const float* bk = (const float*)d_in[6];
  const float* wv = (const float*)d_in[7];
  const float* bv = (const float*)d_in[8];
  const float* wo = (const float*)d_in[9];
  const float* ln1 = (const float*)d_in[10];
  const float* ln2 = (const float*)d_in[11];
  const float* wg = (const float*)d_in[12];
  const float* wu = (const float*)d_in[13];
  const float* wd = (const float*)d_in[14];
  float* out = (float*)d_out;
  char* ws = (char*)d_ws;

  const int M = BB * SS;  // 4096

  // workspace layout (MB offsets)
  f16* wqT = (f16*)ws;                      // 2MB
  f16* wkT = (f16*)(ws + (2u << 20));       // 0.5MB
  f16* wvT = (f16*)(ws + (2560u << 10));    // 0.5MB
  f16* woT = (f16*)(ws + (3u << 20));       // 2MB
  f16* wgT = (f16*)(ws + (5u << 20));       // 8MB
  f16* wuT = (f16*)(ws + (13u << 20));      // 8MB
  f16* wdT = (f16*)(ws + (21u << 20));      // 8MB
  f16* Anh = (f16*)(ws + (29u << 20));      // 8MB [M][1024] f16
  float* Qb = (float*)(ws + (37u << 20));   // 16MB (dead after rope)
  float* Kb = (float*)(ws + (53u << 20));   // 4MB (dead after rope)
  float* Vb = (float*)(ws + (57u << 20));   // 4MB (dead after vtrans)
  f16* Qh = (f16*)(ws + (61u << 20));       // 8MB (dead after attn)
  f16* Kh = (f16*)(ws + (69u << 20));       // 2MB (dead after attn)
  f16* Vt = (f16*)(ws + (71u << 20));       // 2MB (dead after attn)
  f16* CTXh = (f16*)(ws + (73u << 20));     // 8MB
  f16* ACTh = (f16*)(ws + (37u << 20));     // 32MB, aliases Qb..Qh (dead)

  transpose_cast_kernel<<<dim3(DD / 64, DD / 64), 256, 0, stream>>>(wq, wqT, DD, DD);
  transpose_cast_kernel<<<dim3(4, DD / 64), 256, 0, stream>>>(wk, wkT, DD, 256);
  transpose_cast_kernel<<<dim3(4, DD / 64), 256, 0, stream>>>(wv, wvT, DD, 256);
  transpose_cast_kernel<<<dim3(DD / 64, DD / 64), 256, 0, stream>>>(wo, woT, DD, DD);
  transpose_cast_kernel<<<dim3(FFD / 64, DD / 64), 256, 0, stream>>>(wg, wgT, DD, FFD);
  transpose_cast_kernel<<<dim3(FFD / 64, DD / 64), 256, 0, stream>>>(wu, wuT, DD, FFD);
  transpose_cast_kernel<<<dim3(DD / 64, FFD / 64), 256, 0, stream>>>(wd, wdT, FFD, DD);

  rmsnorm_kernel<<<M, 256, 0, stream>>>(hidden, ln1, Anh, DD);
  mfma_gemm<false><<<dim3((HH * HDIM) / 128, M / 128), 256, 0, stream>>>(
      Anh, wqT, nullptr, bq, nullptr, Qb, nullptr, M, HH * HDIM, DD);
  mfma_gemm<false><<<dim3((HKVN * HDIM) / 128, M / 128), 256, 0, stream>>>(
      Anh, wkT, nullptr, bk, nullptr, Kb, nullptr, M, HKVN * HDIM, DD);
  mfma_gemm<false><<<dim3((HKVN * HDIM) / 128, M / 128), 256, 0, stream>>>(
      Anh, wvT, nullptr, bv, nullptr, Vb, nullptr, M, HKVN * HDIM, DD);
  rope_cast_kernel<<<(BB * SS * (HH + HKVN) * 32) / 256, 256, 0, stream>>>(
      Qb, Kb, cos_t, sin_t, Qh, Kh);
  vtrans_kernel<<<BB * HKVN * (SS / 64), 256, 0, stream>>>(Vb, Vt);
  attn_kernel<<<BB * HKVN * (SS / 32), 256, 0, stream>>>(Qh, Kh, Vt, CTXh);
  mfma_gemm<false><<<dim3(DD / 128, M / 128), 256, 0, stream>>>(
      CTXh, woT, nullptr, nullptr, hidden, out, nullptr, M, DD, DD);
  rmsnorm_kernel<<<M, 256, 0, stream>>>(out, ln2, Anh, DD);
  mfma_gemm<true><<<dim3(FFD / 128, M / 128), 256, 0, stream>>>(
      Anh, wgT, wuT, nullptr, nullptr, nullptr, ACTh, M, FFD, DD);
  mfma_gemm<false><<<dim3(DD / 128, M / 128), 256, 0, stream>>>(
      ACTh, wdT, nullptr, nullptr, out, out, nullptr, M, DD, FFD);
}

// Round 5
// 295.703 us; speedup vs baseline: 19.0132x; 1.3503x over previous
//
#include <hip/hip_runtime.h>
#include <hip/hip_bf16.h>
#include <hip/hip_fp16.h>
#include <math.h>

// Qwen2 decoder layer, MI355X. Round 5: counted-vmcnt pipelined GEMMs,
// 8-wave gate/up, fused QKV, split-K down-proj. Flash attention from R4.
// B=2 S=2048 D=1024 H=16 HKV=4 HD=64 FF=4096 WINDOW=1024
#define BB 2
#define SS 2048
#define DD 1024
#define HH 16
#define HKVN 4
#define HDIM 64
#define FFD 4096
#define WND 1024
#define EPSF 1e-6f

typedef _Float16 f16;
typedef _Float16 half8 __attribute__((ext_vector_type(8)));
typedef float f32x4 __attribute__((ext_vector_type(4)));
typedef unsigned int u32;

#define GLOAD_LDS(gp, lp)                                                  \
  __builtin_amdgcn_global_load_lds(                                        \
      (const __attribute__((address_space(1))) u32*)(gp),                  \
      (__attribute__((address_space(3))) u32*)(lp), 16, 0, 0)

static __device__ inline u32 pack2(float a, float b) {
  unsigned short ua = __builtin_bit_cast(unsigned short, (f16)a);
  unsigned short ub = __builtin_bit_cast(unsigned short, (f16)b);
  return (u32)ua | ((u32)ub << 16);
}

// ---------------- Weight transpose+cast: Wt[N][K] f16 = W[K][N] f32 --------
__global__ __launch_bounds__(256) void transpose_cast_kernel(
    const float* __restrict__ W, f16* __restrict__ Wt, int K, int N) {
  __shared__ float tile[64][65];
  int k0 = blockIdx.y * 64, n0 = blockIdx.x * 64;
  int tx = threadIdx.x & 63, tr = threadIdx.x >> 6;
#pragma unroll
  for (int i = 0; i < 16; i++) {
    int r = tr + i * 4;
    tile[r][tx] = W[(size_t)(k0 + r) * N + n0 + tx];
  }
  __syncthreads();
#pragma unroll
  for (int i = 0; i < 16; i++) {
    int r = tr + i * 4;  // n-local
    Wt[(size_t)(n0 + r) * K + k0 + tx] = (f16)tile[tx][r];
  }
}

// ---------------- concat bias [bq|bk|bv] -> 1536 floats ----------------
__global__ __launch_bounds__(256) void biascat_kernel(
    const float* __restrict__ bq, const float* __restrict__ bk,
    const float* __restrict__ bv, float* __restrict__ o) {
  int i = blockIdx.x * 256 + threadIdx.x;
  if (i < 1024)
    o[i] = bq[i];
  else if (i < 1280)
    o[i] = bk[i - 1024];
  else if (i < 1536)
    o[i] = bv[i - 1280];
}

// ---------------- RMSNorm: fp32 in -> f16 out ----------------
__global__ __launch_bounds__(256) void rmsnorm_kernel(
    const float* __restrict__ x, const float* __restrict__ w,
    f16* __restrict__ out, int d) {
  int row = blockIdx.x;
  const float* xr = x + (size_t)row * d;
  float ss = 0.f;
  for (int i = threadIdx.x; i < d; i += blockDim.x) {
    float v = xr[i];
    ss += v * v;
  }
  __shared__ float red[8];
  for (int o = 32; o > 0; o >>= 1) ss += __shfl_down(ss, o, 64);
  int wid = threadIdx.x >> 6, lane = threadIdx.x & 63;
  if (lane == 0) red[wid] = ss;
  __syncthreads();
  if (threadIdx.x == 0) {
    float t = 0.f;
    int nw = blockDim.x >> 6;
    for (int i = 0; i < nw; i++) t += red[i];
    red[0] = rsqrtf(t / (float)d + EPSF);
  }
  __syncthreads();
  float rs = red[0];
  f16* orow = out + (size_t)row * d;
  for (int i = threadIdx.x; i < d; i += blockDim.x) {
    orow[i] = (f16)(xr[i] * rs * w[i]);
  }
}

// ---------------- f16 MFMA GEMM, 3-buffer counted-vmcnt pipeline ----------
// C = A[M][K] @ Bt[N][K]^T (+bias) (+resid) -> fp32. Optional split-K via
// blockIdx.z (KL = K-chunk length); partials to Cf (z=0) / Cf2 (z=1).
__global__ __launch_bounds__(256) void mfma_gemm(
    const f16* __restrict__ A, const f16* __restrict__ Bt,
    const float* __restrict__ bias, const float* __restrict__ resid,
    float* __restrict__ Cf, float* __restrict__ Cf2, int M, int N, int K,
    int KL) {
  __shared__ __align__(16) char smem[3 * 16384];
  const int tid = threadIdx.x;
  const int lane = tid & 63;
  const int wid = tid >> 6;
  const int wr = wid >> 1, wc = wid & 1;
  const int row0 = blockIdx.y * 128, col0 = blockIdx.x * 128;
  const int koff = blockIdx.z * KL;

  f32x4 acc[4][4];
#pragma unroll
  for (int m = 0; m < 4; m++)
#pragma unroll
    for (int n = 0; n < 4; n++) acc[m][n] = (f32x4){0.f, 0.f, 0.f, 0.f};

  auto stage = [&](int buf, int k0) {
    char* base = smem + buf * 16384;
#pragma unroll
    for (int q = 0; q < 2; q++) {
      int s = wid * 128 + q * 64 + lane;
      int r = s >> 2;
      int cg = (s & 3) ^ ((r >> 1) & 3);
      size_t goff = (size_t)r * K + k0 + cg * 8;
      u32 ldsb = (u32)((wid * 2 + q) * 1024);
      GLOAD_LDS(A + (size_t)row0 * K + goff, base + ldsb);
      GLOAD_LDS(Bt + (size_t)col0 * K + goff, base + 8192 + ldsb);
    }
  };
  auto off = [&](int r, int g) -> int {
    return r * 64 + ((g ^ ((r >> 1) & 3)) << 4);
  };

  const int nt = KL / 32;
  stage(0, koff);
  if (nt > 1) stage(1, koff + 32);
  int cur = 0;
  const int g = lane >> 4, l15 = lane & 15;
  for (int t = 0; t < nt; t++) {
    // retire stage t (keep stage t+1 in flight across the barrier)
    if (t + 1 < nt)
      asm volatile("s_waitcnt vmcnt(4)" ::: "memory");
    else
      asm volatile("s_waitcnt vmcnt(0)" ::: "memory");
    asm volatile("s_waitcnt lgkmcnt(0)" ::: "memory");
    __builtin_amdgcn_sched_barrier(0);
    __builtin_amdgcn_s_barrier();
    __builtin_amdgcn_sched_barrier(0);
    const char* base = smem + cur * 16384;
    half8 af[4], bf[4];
#pragma unroll
    for (int m = 0; m < 4; m++) {
      int r = wr * 64 + m * 16 + l15;
      af[m] = *(const half8*)(base + off(r, g));
    }
#pragma unroll
    for (int n = 0; n < 4; n++) {
      int c = wc * 64 + n * 16 + l15;
      bf[n] = *(const half8*)(base + 8192 + off(c, g));
    }
    if (t + 2 < nt) {
      int nb = cur + 2;
      if (nb >= 3) nb -= 3;
      stage(nb, koff + (t + 2) * 32);
    }
    __builtin_amdgcn_s_setprio(1);
#pragma unroll
    for (int m = 0; m < 4; m++)
#pragma unroll
      for (int n = 0; n < 4; n++)
        acc[m][n] =
            __builtin_amdgcn_mfma_f32_16x16x32_f16(af[m], bf[n], acc[m][n], 0, 0, 0);
    __builtin_amdgcn_s_setprio(0);
    cur = (cur + 1 == 3) ? 0 : cur + 1;
  }

  float* cw = (blockIdx.z == 0) ? Cf : Cf2;
#pragma unroll
  for (int m = 0; m < 4; m++) {
#pragma unroll
    for (int n = 0; n < 4; n++) {
#pragma unroll
      for (int v = 0; v < 4; v++) {
        int r = row0 + wr * 64 + m * 16 + (lane >> 4) * 4 + v;
        int c = col0 + wc * 64 + n * 16 + (lane & 15);
        float vv = acc[m][n][v];
        if (bias) vv += bias[c];
        if (resid) vv += resid[(size_t)r * N + c];
        cw[(size_t)r * N + c] = vv;
      }
    }
  }
}

// ---------------- gate/up dual GEMM, 8 waves, pipelined ----------------
// ACT = silu(A@Wg^T) * (A@Wu^T), f16 out. 128x128 tile, wave-tile 32x64.
__global__ __launch_bounds__(512) void gateup_gemm(
    const f16* __restrict__ A, const f16* __restrict__ Wg,
    const f16* __restrict__ Wu, f16* __restrict__ ACT, int M, int N, int K) {
  __shared__ __align__(16) char smem[3 * 24576];
  const int tid = threadIdx.x;
  const int lane = tid & 63;
  const int wid = tid >> 6;  // 0..7
  const int wr = wid >> 1;   // 0..3 (rows of 32)
  const int wc = wid & 1;    // 0..1 (cols of 64)
  const int row0 = blockIdx.y * 128, col0 = blockIdx.x * 128;

  f32x4 accg[2][4], accu[2][4];
#pragma unroll
  for (int m = 0; m < 2; m++)
#pragma unroll
    for (int n = 0; n < 4; n++) {
      accg[m][n] = (f32x4){0.f, 0.f, 0.f, 0.f};
      accu[m][n] = (f32x4){0.f, 0.f, 0.f, 0.f};
    }

  auto stage = [&](int buf, int k0) {
    char* base = smem + buf * 24576;
    int s = tid;  // 512 slots x 16B = one 8KB tile each
    int r = s >> 2;
    int cg = (s & 3) ^ ((r >> 1) & 3);
    size_t goff = (size_t)r * K + k0 + cg * 8;
    u32 ldsb = (u32)(wid * 1024);
    GLOAD_LDS(A + (size_t)row0 * K + goff, base + ldsb);
    GLOAD_LDS(Wg + (size_t)col0 * K + goff, base + 8192 + ldsb);
    GLOAD_LDS(Wu + (size_t)col0 * K + goff, base + 16384 + ldsb);
  };
  auto off = [&](int r, int g) -> int {
    return r * 64 + ((g ^ ((r >> 1) & 3)) << 4);
  };

  const int nt = K / 32;
  stage(0, 0);
  if (nt > 1) stage(1, 32);
  int cur = 0;
  const int g = lane >> 4, l15 = lane & 15;
  for (int t = 0; t < nt; t++) {
    if (t + 1 < nt)
      asm volatile("s_waitcnt vmcnt(3)" ::: "memory");
    else
      asm volatile("s_waitcnt vmcnt(0)" ::: "memory");
    asm volatile("s_waitcnt lgkmcnt(0)" ::: "memory");
    __builtin_amdgcn_sched_barrier(0);
    __builtin_amdgcn_s_barrier();
    __builtin_amdgcn_sched_barrier(0);
    const char* base = smem + cur * 24576;
    half8 af[2], gf[4], uf[4];
#pragma unroll
    for (int m = 0; m < 2; m++) {
      int r = wr * 32 + m * 16 + l15;
      af[m] = *(const half8*)(base + off(r, g));
    }
#pragma unroll
    for (int n = 0; n < 4; n++) {
      int c = wc * 64 + n * 16 + l15;
      gf[n] = *(const half8*)(base + 8192 + off(c, g));
      uf[n] = *(const half8*)(base + 16384 + off(c, g));
    }
    if (t + 2 < nt) {
      int nb = cur + 2;
      if (nb >= 3) nb -= 3;
      stage(nb, (t + 2) * 32);
    }
    __builtin_amdgcn_s_setprio(1);
#pragma unroll
    for (int m = 0; m < 2; m++)
#pragma unroll
      for (int n = 0; n < 4; n++) {
        accg[m][n] =
            __builtin_amdgcn_mfma_f32_16x16x32_f16(af[m], gf[n], accg[m][n], 0, 0, 0);
        accu[m][n] =
            __builtin_amdgcn_mfma_f32_16x16x32_f16(af[m], uf[n], accu[m][n], 0, 0, 0);
      }
    __builtin_amdgcn_s_setprio(0);
    cur = (cur + 1 == 3) ? 0 : cur + 1;
  }

#pragma unroll
  for (int m = 0; m < 2; m++) {
#pragma unroll
    for (int n = 0; n < 4; n++) {
#pragma unroll
      for (int v = 0; v < 4; v++) {
        int r = row0 + wr * 32 + m * 16 + (lane >> 4) * 4 + v;
        int c = col0 + wc * 64 + n * 16 + (lane & 15);
        float gg = accg[m][n][v];
        float uu = accu[m][n][v];
        float sv = gg / (1.f + __expf(-gg));
        ACT[(size_t)r * N + c] = (f16)(sv * uu);
      }
    }
  }
}

// ---------------- out += P0 + P1 (float4 grid-stride) ----------------
__global__ __launch_bounds__(256) void addreduce_kernel(
    const float* __restrict__ P0, const float* __restrict__ P1,
    float* __restrict__ out, int n4) {
  int idx = blockIdx.x * 256 + threadIdx.x;
  for (int i = idx; i < n4; i += gridDim.x * 256) {
    float4 a = ((const float4*)P0)[i];
    float4 b = ((const float4*)P1)[i];
    float4 o = ((float4*)out)[i];
    o.x += a.x + b.x;
    o.y += a.y + b.y;
    o.z += a.z + b.z;
    o.w += a.w + b.w;
    ((float4*)out)[i] = o;
  }
}

// ---------------- RoPE + cast from fused QKV [M][1536] fp32 ----------------
__global__ __launch_bounds__(256) void rope_cast_kernel(
    const float* __restrict__ QKV, const float* __restrict__ cos_t,
    const float* __restrict__ sin_t, f16* __restrict__ Qh,
    f16* __restrict__ Kh) {
  int idx = blockIdx.x * blockDim.x + threadIdx.x;
  int d = idx & 31;
  int rest = idx >> 5;
  int head = rest % (HH + HKVN);
  int bs = rest / (HH + HKVN);
  int s = bs % SS;
  float c = cos_t[s * HDIM + d];
  float sn = sin_t[s * HDIM + d];
  const float* rowp = QKV + (size_t)bs * 1536;
  if (head < HH) {
    const float* base = rowp + head * HDIM;
    float x1 = base[d], x2 = base[d + 32];
    f16* ob = Qh + ((size_t)bs * HH + head) * HDIM;
    ob[d] = (f16)((x1 * c - x2 * sn) * 0.125f);
    ob[d + 32] = (f16)((x2 * c + x1 * sn) * 0.125f);
  } else {
    int hk = head - HH;
    const float* base = rowp + 1024 + hk * HDIM;
    float x1 = base[d], x2 = base[d + 32];
    f16* ob = Kh + ((size_t)bs * HKVN + hk) * HDIM;
    ob[d] = (f16)(x1 * c - x2 * sn);
    ob[d + 32] = (f16)(x2 * c + x1 * sn);
  }
}

// ---------------- V transpose+cast from QKV cols 1280..1535 ----------------
__global__ __launch_bounds__(256) void vtrans_kernel(
    const float* __restrict__ QKV, f16* __restrict__ Vt) {
  __shared__ float tile[64][65];
  int st = blockIdx.x & 31;
  int hk = (blockIdx.x >> 5) & 3;
  int b = blockIdx.x >> 7;
  int s0 = st * 64;
  int tid = threadIdx.x;
  int r = tid >> 2, cg = tid & 3;
#pragma unroll
  for (int i = 0; i < 4; i++) {
    int c0 = cg * 16 + i * 4;
    float4 vv = *(const float4*)(QKV + (size_t)(b * SS + s0 + r) * 1536 + 1280 +
                                 hk * HDIM + c0);
    tile[r][c0 + 0] = vv.x;
    tile[r][c0 + 1] = vv.y;
    tile[r][c0 + 2] = vv.z;
    tile[r][c0 + 3] = vv.w;
  }
  __syncthreads();
  int dd = tid >> 2, sg = tid & 3;
#pragma unroll
  for (int i = 0; i < 4; i++) {
    int c0 = sg * 16 + i * 4;
    u32 w0 = pack2(tile[c0 + 0][dd], tile[c0 + 1][dd]);
    u32 w1 = pack2(tile[c0 + 2][dd], tile[c0 + 3][dd]);
    *(int2*)(Vt + ((size_t)(b * HKVN + hk) * HDIM + dd) * SS + s0 + c0) =
        make_int2((int)w0, (int)w1);
  }
}

// ---------------- Flash attention, MFMA 16x16x32 f16 (R4) ----------------
__global__ __launch_bounds__(256) void attn_kernel(
    const f16* __restrict__ Qh, const f16* __restrict__ Kh,
    const f16* __restrict__ Vt, f16* __restrict__ O) {
  __shared__ __align__(16) char smem[2 * 16384 + 4 * 4608];
  const int tid = threadIdx.x;
  const int lane = tid & 63;
  const int wid = tid >> 6;
  const int l15 = lane & 15;
  const int g = lane >> 4;
  int qt = blockIdx.x & 63;
  int hk = (blockIdx.x >> 6) & 3;
  int b = blockIdx.x >> 8;
  int s0 = qt * 32;
  int h = hk * 4 + wid;

  half8 qf[2][2];
#pragma unroll
  for (int n = 0; n < 2; n++) {
    int q = s0 + n * 16 + l15;
    const f16* qp = Qh + (((size_t)b * SS + q) * HH + h) * HDIM;
#pragma unroll
    for (int kk = 0; kk < 2; kk++) qf[n][kk] = *(const half8*)(qp + kk * 32 + g * 8);
  }

  const int tb = (s0 >= WND) ? ((s0 - (WND - 1)) >> 6) : 0;
  const int te = (s0 + 31) >> 6;

  f32x4 acc_o[2][4];
#pragma unroll
  for (int m2 = 0; m2 < 2; m2++)
#pragma unroll
    for (int n = 0; n < 4; n++) acc_o[m2][n] = (f32x4){0.f, 0.f, 0.f, 0.f};
  float mrun[2] = {-1e30f, -1e30f};
  float lrun[2] = {0.f, 0.f};

  char* pw = smem + 32768 + wid * 4608;

  auto stage = [&](int buf, int tt) {
    int jt0 = tt * 64;
    char* kbase = smem + buf * 16384;
#pragma unroll
    for (int q2 = 0; q2 < 2; q2++) {
      int slot = (wid * 2 + q2) * 64 + lane;
      int r = slot >> 3, c = slot & 7;
      int cc = c ^ (r & 7);
      u32 ldsb = (u32)((wid * 2 + q2) * 1024);
      const f16* gk =
          Kh + ((size_t)(b * SS + jt0 + r) * HKVN + hk) * HDIM + cc * 8;
      GLOAD_LDS(gk, kbase + ldsb);
      const f16* gv =
          Vt + ((size_t)(b * HKVN + hk) * HDIM + r) * SS + jt0 + cc * 8;
      GLOAD_LDS(gv, kbase + 8192 + ldsb);
    }
  };

  stage(0, tb);
  __syncthreads();
  for (int tt = tb; tt <= te; tt++) {
    int buf = (tt - tb) & 1;
    if (tt < te) stage(buf ^ 1, tt + 1);
    const char* kb = smem + buf * 16384;
    const char* vbp = kb + 8192;
    int jt0 = tt * 64;

    f32x4 acc_s[4][2];
#pragma unroll
    for (int m = 0; m < 4; m++)
#pragma unroll
      for (int n = 0; n < 2; n++) acc_s[m][n] = (f32x4){0.f, 0.f, 0.f, 0.f};
#pragma unroll
    for (int kk = 0; kk < 2; kk++) {
      half8 af[4];
#pragma unroll
      for (int m = 0; m < 4; m++) {
        int key = m * 16 + l15;
        af[m] = *(const half8*)(kb + key * 128 + (((kk * 4 + g) ^ (key & 7)) << 4));
      }
#pragma unroll
      for (int m = 0; m < 4; m++)
#pragma unroll
        for (int n = 0; n < 2; n++)
          acc_s[m][n] = __builtin_amdgcn_mfma_f32_16x16x32_f16(af[m], qf[n][kk],
                                                               acc_s[m][n], 0, 0, 0);
    }

    float tmax[2] = {-1e38f, -1e38f};
#pragma unroll
    for (int m = 0; m < 4; m++)
#pragma unroll
      for (int n = 0; n < 2; n++)
#pragma unroll
        for (int v = 0; v < 4; v++) {
          int j = jt0 + m * 16 + g * 4 + v;
          int q = s0 + n * 16 + l15;
          float s = acc_s[m][n][v];
          s = ((unsigned)(q - j) < (unsigned)WND) ? s : -1e38f;
          acc_s[m][n][v] = s;
          tmax[n] = fmaxf(tmax[n], s);
        }
#pragma unroll
    for (int n = 0; n < 2; n++) {
      tmax[n] = fmaxf(tmax[n], __shfl_xor(tmax[n], 16, 64));
      tmax[n] = fmaxf(tmax[n], __shfl_xor(tmax[n], 32, 64));
    }
    float corr[2], rs[2];
#pragma unroll
    for (int n = 0; n < 2; n++) {
      float mn = fmaxf(mrun[n], tmax[n]);
      corr[n] = __expf(mrun[n] - mn);
      mrun[n] = mn;
      rs[n] = 0.f;
    }
#pragma unroll
    for (int m = 0; m < 4; m++)
#pragma unroll
      for (int n = 0; n < 2; n++) {
        float p0 = __expf(acc_s[m][n][0] - mrun[n]);
        float p1 = __expf(acc_s[m][n][1] - mrun[n]);
        float p2 = __expf(acc_s[m][n][2] - mrun[n]);
        float p3 = __expf(acc_s[m][n][3] - mrun[n]);
        rs[n] += (p0 + p1) + (p2 + p3);
        *(int2*)(pw + (n * 16 + l15) * 144 + (m * 16 + g * 4) * 2) =
            make_int2((int)pack2(p0, p1), (int)pack2(p2, p3));
      }
#pragma unroll
    for (int n = 0; n < 2; n++) {
      rs[n] += __shfl_xor(rs[n], 16, 64);
      rs[n] += __shfl_xor(rs[n], 32, 64);
      lrun[n] = lrun[n] * corr[n] + rs[n];
    }
#pragma unroll
    for (int m2 = 0; m2 < 2; m2++)
#pragma unroll
      for (int v = 0; v < 4; v++) {
        float cw = __shfl(corr[m2], g * 4 + v, 64);
#pragma unroll
        for (int n = 0; n < 4; n++) acc_o[m2][n][v] *= cw;
      }
#pragma unroll
    for (int kk = 0; kk < 2; kk++) {
      half8 ap[2], vf[4];
#pragma unroll
      for (int m2 = 0; m2 < 2; m2++)
        ap[m2] = *(const half8*)(pw + (m2 * 16 + l15) * 144 + (kk * 32 + g * 8) * 2);
#pragma unroll
      for (int n = 0; n < 4; n++) {
        int d = n * 16 + l15;
        vf[n] = *(const half8*)(vbp + d * 128 + (((kk * 4 + g) ^ (d & 7)) << 4));
      }
#pragma unroll
      for (int m2 = 0; m2 < 2; m2++)
#pragma unroll
        for (int n = 0; n < 4; n++)
          acc_o[m2][n] = __builtin_amdgcn_mfma_f32_16x16x32_f16(ap[m2], vf[n],
                                                                acc_o[m2][n], 0, 0, 0);
    }
    __syncthreads();
  }

#pragma unroll
  for (int m2 = 0; m2 < 2; m2++)
#pragma unroll
    for (int v = 0; v < 4; v++) {
      float li = __shfl(lrun[m2], g * 4 + v, 64);
      float inv = 1.f / li;
      int q = s0 + m2 * 16 + g * 4 + v;
#pragma unroll
      for (int n = 0; n < 4; n++) {
        int d = n * 16 + l15;
        O[(((size_t)b * SS + q) * HH + h) * HDIM + d] =
            (f16)(acc_o[m2][n][v] * inv);
      }
    }
}

extern "C" void kernel_launch(void* const* d_in, const int* in_sizes, int n_in,
                              void* d_out, int out_size, void* d_ws,
                              size_t ws_size, hipStream_t stream) {
  const float* hidden = (const float*)d_in[0];
  const float* cos_t = (const float*)d_in[1];
  const float* sin_t = (const float*)d_in[2];
  const float* wq = (const float*)d_in[3];
  const float* bq = (const float*)d_in[4];
  const float* wk = (const float*)d_in[5];
  const float* bk = (const float*)d_in[6];
  const float* wv = (const float*)d_in[7];
  const float* bv = (const float*)d_in[8];
  const float* wo = (const float*)d_in[9];
  const float* ln1 = (const float*)d_in[10];
  const float* ln2 = (const float*)d_in[11];
  const float* wg = (const float*)d_in[12];
  const float* wu = (const float*)d_in[13];
  const float* wd = (const float*)d_in[14];
  float* out = (float*)d_out;
  char* ws = (char*)d_ws;

  const int M = BB * SS;  // 4096

  // workspace layout (MB offsets; total ~81MB)
  f16* qkvT = (f16*)ws;                     // [1536][1024] 3MB
  f16* woT = (f16*)(ws + (3u << 20));       // [1024][1024] 2MB
  f16* wgT = (f16*)(ws + (5u << 20));       // 8MB  \ P1 region after gateup
  f16* wuT = (f16*)(ws + (13u << 20));      // 8MB  /
  f16* wdT = (f16*)(ws + (21u << 20));      // 8MB
  f16* Anh = (f16*)(ws + (29u << 20));      // 8MB  \ P0 region after gateup
  f16* CTXh = (f16*)(ws + (37u << 20));     // 8MB  /
  float* QKVb = (float*)(ws + (45u << 20)); // [M][1536] 24MB (dead after vtrans)
  f16* Qh = (f16*)(ws + (69u << 20));       // 8MB (dead after attn)
  f16* Kh = (f16*)(ws + (77u << 20));       // 2MB (dead after attn)
  f16* Vt = (f16*)(ws + (79u << 20));       // 2MB (dead after attn)
  f16* ACTh = (f16*)(ws + (45u << 20));     // 32MB, aliases QKVb+Qh (dead)
  float* P0 = (float*)(ws + (29u << 20));   // 16MB over Anh+CTXh (dead)
  float* P1 = (float*)(ws + (5u << 20));    // 16MB over wgT+wuT (dead)
  float* biasC = (float*)(ws + (81u << 20));// 6KB

  // weights -> f16 [N][K]
  transpose_cast_kernel<<<dim3(DD / 64, DD / 64), 256, 0, stream>>>(wq, qkvT, DD, DD);
  transpose_cast_kernel<<<dim3(4, DD / 64), 256, 0, stream>>>(
      wk, qkvT + (size_t)1024 * DD, DD, 256);
  transpose_cast_kernel<<<dim3(4, DD / 64), 256, 0, stream>>>(
      wv, qkvT + (size_t)1280 * DD, DD, 256);
  transpose_cast_kernel<<<dim3(DD / 64, DD / 64), 256, 0, stream>>>(wo, woT, DD, DD);
  transpose_cast_kernel<<<dim3(FFD / 64, DD / 64), 256, 0, stream>>>(wg, wgT, DD, FFD);
  transpose_cast_kernel<<<dim3(FFD / 64, DD / 64), 256, 0, stream>>>(wu, wuT, DD, FFD);
  transpose_cast_kernel<<<dim3(DD / 64, FFD / 64), 256, 0, stream>>>(wd, wdT, FFD, DD);
  biascat_kernel<<<6, 256, 0, stream>>>(bq, bk, bv, biasC);

  // 1) RMSNorm 1 -> f16
  rmsnorm_kernel<<<M, 256, 0, stream>>>(hidden, ln1, Anh, DD);
  // 2) fused QKV projection -> fp32 [M][1536]
  mfma_gemm<<<dim3(1536 / 128, M / 128, 1), 256, 0, stream>>>(
      Anh, qkvT, biasC, nullptr, QKVb, nullptr, M, 1536, DD, DD);
  // 3) RoPE -> Qh (pre-scaled), Kh ; V -> Vt
  rope_cast_kernel<<<(BB * SS * (HH + HKVN) * 32) / 256, 256, 0, stream>>>(
      QKVb, cos_t, sin_t, Qh, Kh);
  vtrans_kernel<<<BB * HKVN * (SS / 64), 256, 0, stream>>>(QKVb, Vt);
  // 4) Flash attention -> f16 CTX
  attn_kernel<<<BB * HKVN * (SS / 32), 256, 0, stream>>>(Qh, Kh, Vt, CTXh);
  // 5) Output projection + residual -> d_out
  mfma_gemm<<<dim3(DD / 128, M / 128, 1), 256, 0, stream>>>(
      CTXh, woT, nullptr, hidden, out, nullptr, M, DD, DD, DD);
  // 6) RMSNorm 2 -> f16
  rmsnorm_kernel<<<M, 256, 0, stream>>>(out, ln2, Anh, DD);
  // 7) gate/up dual GEMM + SiLU*up -> f16 ACT
  gateup_gemm<<<dim3(FFD / 128, M / 128), 512, 0, stream>>>(Anh, wgT, wuT, ACTh,
                                                            M, FFD, DD);
  // 8) down-proj split-K=2 -> partials, then out += P0 + P1
  mfma_gemm<<<dim3(DD / 128, M / 128, 2), 256, 0, stream>>>(
      ACTh, wdT, nullptr, nullptr, P0, P1, M, DD, FFD, FFD / 2);
  addreduce_kernel<<<2048, 256, 0, stream>>>(P0, P1, out, M * DD / 4);
}